// Round 2
// baseline (294.653 us; speedup 1.0000x reference)
//
#include <hip/hip_runtime.h>
#include <math.h>

#define SEQ 2048
#define DIM 1024

typedef __attribute__((ext_vector_type(8))) _Float16 half8;
typedef __attribute__((ext_vector_type(4))) float f32x4;

__device__ __forceinline__ unsigned short f2h(float f) {
    union { _Float16 h; unsigned short u; } c; c.h = (_Float16)f;
    return c.u;
}
__device__ __forceinline__ float h2f(unsigned short u) {
    union { unsigned short u2; _Float16 h; } c; c.u2 = u;
    return (float)c.h;
}
__device__ __forceinline__ float gmask(int k) {
    float t = ((float)k - 1024.0f) * (1.0f / 512.0f);
    return expf(-0.5f * t * t);
}
__device__ __forceinline__ void glds16(const unsigned short* gp, unsigned short* lp) {
    __builtin_amdgcn_global_load_lds((const __attribute__((address_space(1))) void*)gp,
                                     (__attribute__((address_space(3))) void*)lp, 16, 0, 0);
}

// Stage one 128x64 fp16 unit (16 KB) global->LDS; 512 threads, 2 loads/thread.
// LDS[row][slot] holds global segment slot^(row&7) (pre-swizzled source, linear
// dest -- rule #21). This swizzle measured 0 bank conflicts with the 16x16
// fragment read pattern below; do not change either side alone.
__device__ __forceinline__ void stage_unit(const unsigned short* __restrict__ g, int ldK,
                                           unsigned short* lds, int wave, int lane) {
    int row = wave * 16 + (lane >> 3);
    int seg = (lane & 7) ^ (lane >> 3);
    const unsigned short* gp = g + (long)row * ldK + seg * 8;
    unsigned short* lp = lds + wave * 1024;
    glds16(gp, lp);
    glds16(gp + 8 * (long)ldK, lp + 512);
}

enum { EPI_QKV = 0, EPI_EXP = 1, EPI_PV = 2, EPI_OUT = 3 };

#define BAR() __builtin_amdgcn_s_barrier()
#define LGKM0() asm volatile("s_waitcnt lgkmcnt(0)" ::: "memory")
#define VMC(N) asm volatile("s_waitcnt vmcnt(" #N ")" ::: "memory")

// C = A @ B^T, BM=128 x BN=256 x BK=64 tiles, 8 waves (2M x 4N), 512 threads.
// Single-phase K-loop with cross-barrier staging (R1 post-mortem: 4-phase split
// at this geometry = 8 MFMA/barrier-pair -> sync-bound, MfmaUtil 24%. R0 showed
// 32 MFMA/barrier-pair works; its loss was the vmcnt(0) drain. This round keeps
// R0 granularity + R1's triple buffer and counted vmcnt):
//   per tile: 16 ds_read_b128 (whole fragment set) || 3 stage units of tile t+2
//   -> BAR -> lgkmcnt(0) -> setprio(1) 32xMFMA setprio(0) -> VMC(6) -> BAR
// VMC(6) leaves exactly tile t+2's 6 loads in flight: tile t+1 is fully landed
// when the barrier opens, no drain-to-0 in the steady loop.
// Triple-buffered LDS (3 x 48KB): stage target's last reader finished a full
// tile earlier (race-free; verified passing in R1).
// EPI_QKV: N=3072 packed; writes Q, K, V^T [b][d][s] (+bias from aux).
// EPI_EXP: writes fp16 exp(acc*scale*gmask(n)); accumulates row sums of exp
//          into rsum[b][row] via wave shfl-reduce + atomicAdd (rsum pre-zeroed).
// EPI_PV : writes fp16 acc * (1/rsum[b][row]).
// EPI_OUT: writes fp32 acc + aux(n).
template <int EPI>
__global__ __launch_bounds__(512, 2) void mfma_gemm(
    const unsigned short* __restrict__ A, const unsigned short* __restrict__ Bm,
    const float* __restrict__ aux,
    float* __restrict__ Cf, unsigned short* __restrict__ Ch,
    float* __restrict__ rsum,
    int M, int N, int K, float scale, long sA, long sB, long sC)
{
    __shared__ unsigned short sh[3 * 24576];  // 144 KB: 3 x (A 128x64 + B 256x64)

    const int bz = blockIdx.z;
    const int tid = threadIdx.x;
    const int wave = tid >> 6;
    const int lane = tid & 63;
    const int rb = (wave & 1) * 64;       // wave row offset in 128
    const int cb = (wave >> 1) * 64;      // wave col offset in 256
    const long m0 = (long)blockIdx.y * 128;
    const long n0 = (long)blockIdx.x * 256;
    const int lm = lane & 15;
    const int lk = lane >> 4;

    const unsigned short* pA = A + bz * sA + m0 * K;
    const unsigned short* pB = Bm + bz * sB + n0 * K;

    f32x4 acc[4][4];
#pragma unroll
    for (int i = 0; i < 4; ++i)
#pragma unroll
        for (int j = 0; j < 4; ++j) {
            acc[i][j].x = 0.f; acc[i][j].y = 0.f; acc[i][j].z = 0.f; acc[i][j].w = 0.f;
        }

    // fragment LDS offsets (elems), swizzle applied: frag f, k-step t
    int aoff[4][2], boff[4][2];
#pragma unroll
    for (int f = 0; f < 4; ++f)
#pragma unroll
        for (int t = 0; t < 2; ++t) {
            int ar = rb + f * 16 + lm;
            aoff[f][t] = ar * 64 + (((4 * t + lk) ^ (ar & 7)) << 3);
            int br = cb + f * 16 + lm;
            boff[f][t] = br * 64 + (((4 * t + lk) ^ (br & 7)) << 3);
        }

    const int NT = K >> 6;

    // prologue: stage tiles 0 and 1 fully (A, B-lo, B-hi each = 6 loads/thread)
    stage_unit(pA, K, sh, wave, lane);
    stage_unit(pB, K, sh + 8192, wave, lane);
    stage_unit(pB + 128 * (long)K, K, sh + 16384, wave, lane);
    stage_unit(pA + 64, K, sh + 24576, wave, lane);
    stage_unit(pB + 64, K, sh + 24576 + 8192, wave, lane);
    stage_unit(pB + 128 * (long)K + 64, K, sh + 24576 + 16384, wave, lane);
    VMC(6);   // tile 0 landed; tile 1's 3 units stay in flight
    BAR();

#pragma unroll 1
    for (int t = 0; t < NT; ++t) {
        unsigned short* As = sh + (t % 3) * 24576;
        unsigned short* Bs = As + 8192;
        const int t2 = t + 2;
        const bool st = t2 < NT;                       // block-uniform
        unsigned short* Sd = sh + (t2 % 3) * 24576;

        half8 a[4][2], b[4][2];
        // full fragment set for this tile: 16 x ds_read_b128
#pragma unroll
        for (int kt = 0; kt < 2; ++kt)
#pragma unroll
            for (int f = 0; f < 4; ++f) {
                a[f][kt] = *(const half8*)(As + aoff[f][kt]);
                b[f][kt] = *(const half8*)(Bs + boff[f][kt]);
            }
        // stage all of tile t+2 into the dead buffer (6 glds, in flight
        // across the next two barriers)
        if (st) {
            stage_unit(pA + t2 * 64, K, Sd, wave, lane);
            stage_unit(pB + t2 * 64, K, Sd + 8192, wave, lane);
            stage_unit(pB + 128 * (long)K + t2 * 64, K, Sd + 16384, wave, lane);
        }
        BAR(); LGKM0();
        __builtin_amdgcn_s_setprio(1);
#pragma unroll
        for (int mi = 0; mi < 4; ++mi)
#pragma unroll
            for (int nj = 0; nj < 4; ++nj)
#pragma unroll
                for (int kt = 0; kt < 2; ++kt)
                    acc[mi][nj] = __builtin_amdgcn_mfma_f32_16x16x32_f16(a[mi][kt], b[nj][kt], acc[mi][nj], 0, 0, 0);
        __builtin_amdgcn_s_setprio(0);
        if (t < NT - 2) { VMC(6); } else { VMC(0); }  // tile t+1 fully landed
        BAR();
    }

    // ---- epilogue. C/D layout: col = lane&15, row = (lane>>4)*4 + r  [m89/m91]
    const long MD = 8388608;  // 4*SEQ*DIM
    float* cF = (EPI == EPI_OUT) ? Cf + bz * sC : (float*)nullptr;
    unsigned short* cH = (EPI != EPI_OUT) ? Ch + bz * sC : (unsigned short*)nullptr;

#pragma unroll
    for (int mf = 0; mf < 4; ++mf) {
        long mrow = m0 + rb + mf * 16 + lk * 4;   // rows mrow..mrow+3
        if (EPI == EPI_QKV) {
#pragma unroll
            for (int nf = 0; nf < 4; ++nf) {
                int n = (int)n0 + cb + nf * 16 + lm;
                int sel = n >> 10;   // block-uniform (n0 multiple of 256)
                int n1 = n & 1023;
                float bs = aux[n];
                if (sel < 2) {
                    unsigned short* dst = cH + (long)sel * MD;
#pragma unroll
                    for (int r = 0; r < 4; ++r)
                        dst[(mrow + r) * (long)DIM + n1] = f2h(acc[mf][nf][r] + bs);
                } else {
                    long bb = mrow >> 11, s = mrow & 2047;
                    long idx = 2 * MD + bb * (long)DIM * SEQ + (long)n1 * SEQ + s;
                    unsigned long long pk =
                        (unsigned long long)f2h(acc[mf][nf].x + bs) |
                        ((unsigned long long)f2h(acc[mf][nf].y + bs) << 16) |
                        ((unsigned long long)f2h(acc[mf][nf].z + bs) << 32) |
                        ((unsigned long long)f2h(acc[mf][nf].w + bs) << 48);
                    *(unsigned long long*)(cH + idx) = pk;
                }
            }
        } else if (EPI == EPI_EXP) {
            float rsv[4] = {0.f, 0.f, 0.f, 0.f};
#pragma unroll
            for (int nf = 0; nf < 4; ++nf) {
                int n = (int)n0 + cb + nf * 16 + lm;
                float mult = scale * gmask(n);
#pragma unroll
                for (int r = 0; r < 4; ++r) {
                    float e = expf(acc[mf][nf][r] * mult);
                    unsigned short h = f2h(e);
                    cH[(mrow + r) * (long)N + n] = h;
                    rsv[r] += h2f(h);   // sum the fp16-rounded value (matches PV read)
                }
            }
            // reduce the 4-col partials over the 16 lm-lanes (stays in lk group)
#pragma unroll
            for (int r = 0; r < 4; ++r) {
#pragma unroll
                for (int msk = 1; msk < 16; msk <<= 1)
                    rsv[r] += __shfl_xor(rsv[r], msk, 64);
            }
            if (lm == 0) {
#pragma unroll
                for (int r = 0; r < 4; ++r)
                    atomicAdd(rsum + (long)bz * SEQ + mrow + r, rsv[r]);
            }
        } else if (EPI == EPI_PV) {
#pragma unroll
            for (int r = 0; r < 4; ++r) {
                float inv = 1.0f / rsum[(long)bz * SEQ + mrow + r];
#pragma unroll
                for (int nf = 0; nf < 4; ++nf) {
                    int n = (int)n0 + cb + nf * 16 + lm;
                    cH[(mrow + r) * (long)N + n] = f2h(acc[mf][nf][r] * inv);
                }
            }
        } else {  // EPI_OUT
#pragma unroll
            for (int nf = 0; nf < 4; ++nf) {
                int n = (int)n0 + cb + nf * 16 + lm;
                float bs = aux[n];
#pragma unroll
                for (int r = 0; r < 4; ++r)
                    cF[(mrow + r) * (long)N + n] = acc[mf][nf][r] + bs;
            }
        }
    }
}

// One-shot prep: x -> fp16, pack Wq|Wk|Wv|Wo -> fp16, pack bq|bk|bv -> fp32,
// zero rsum[4*SEQ] (EXP accumulates into it each launch).
__global__ __launch_bounds__(256) void prep(
    const float* __restrict__ x,
    const float* __restrict__ Wq, const float* __restrict__ Wk,
    const float* __restrict__ Wv, const float* __restrict__ Wo,
    const float* __restrict__ b0, const float* __restrict__ b1, const float* __restrict__ b2,
    unsigned short* __restrict__ xh, unsigned short* __restrict__ Wp,
    float* __restrict__ bqkv, float* __restrict__ rsum)
{
    long gid = (long)blockIdx.x * 256 + threadIdx.x;
    if (gid < 3072) {
        int sel = (int)(gid >> 10);
        const float* s = sel == 0 ? b0 : sel == 1 ? b1 : b2;
        bqkv[gid] = s[gid & 1023];
    }
    if (gid < 4 * SEQ) rsum[gid] = 0.f;
    const long NX = 8388608 / 4;   // x float4 count
    const long NW = 1048576 / 4;   // per-weight float4 count (2^18)
    const long total = NX + 4 * NW;
    for (long i = gid; i < total; i += (long)gridDim.x * 256) {
        const float* src; unsigned short* dst; long off;
        if (i < NX) { src = x; dst = xh; off = i; }
        else {
            long wi = i - NX;
            int sel = (int)(wi >> 18);
            src = sel == 0 ? Wq : sel == 1 ? Wk : sel == 2 ? Wv : Wo;
            dst = Wp + ((long)sel << 20);
            off = wi & (NW - 1);
        }
        float4 v = ((const float4*)src)[off];
        unsigned long long p = (unsigned long long)f2h(v.x) | ((unsigned long long)f2h(v.y) << 16) |
                               ((unsigned long long)f2h(v.z) << 32) | ((unsigned long long)f2h(v.w) << 48);
        ((unsigned long long*)dst)[off] = p;
    }
}

extern "C" void kernel_launch(void* const* d_in, const int* in_sizes, int n_in,
                              void* d_out, int out_size, void* d_ws, size_t ws_size,
                              hipStream_t stream)
{
    const float* x  = (const float*)d_in[0];
    const float* Wq = (const float*)d_in[1];
    const float* bq = (const float*)d_in[2];
    const float* Wk = (const float*)d_in[3];
    const float* bk = (const float*)d_in[4];
    const float* Wv = (const float*)d_in[5];
    const float* bv = (const float*)d_in[6];
    const float* Wo = (const float*)d_in[7];
    const float* bo = (const float*)d_in[8];
    float* out = (float*)d_out;

    const long MD = 4L * SEQ * DIM;    // 8M
    const long WW = (long)DIM * DIM;   // 1M
    const long SD = (long)SEQ * DIM, SS = (long)SEQ * SEQ;

    unsigned short* xh   = (unsigned short*)d_ws;           // 16 MB
    unsigned short* Wp   = xh + MD;                         // 8 MB (Wqkv|Wo fp16)
    unsigned short* Woh  = Wp + 3 * WW;
    float* bqkv          = (float*)(Wp + 4 * WW);           // 3072 (+pad)
    unsigned short* Qh   = (unsigned short*)(bqkv + 4096);  // Q|K|VT contiguous 48 MB
    unsigned short* VT   = Qh + 2 * MD;                     // [B][D][S]
    unsigned short* expS = Qh + 3 * MD;                     // 33.5 MB
    float* rsum          = (float*)(expS + 4 * SS);         // 4*SEQ fp32 (32 KB)
    unsigned short* O1   = xh;                              // alias: x dead after QKV

    dim3 blk(512);
    prep<<<4096, dim3(256), 0, stream>>>(x, Wq, Wk, Wv, Wo, bq, bk, bv, xh, Wp, bqkv, rsum);

    // QKV fused: [8192,3072] = x @ Wqkv^T + bqkv -> Q, K, V^T   (768 blocks)
    mfma_gemm<EPI_QKV><<<dim3(3 * DIM / 256, (4 * SEQ) / 128, 1), blk, 0, stream>>>(
        xh, Wp, bqkv, nullptr, Qh, nullptr, 4 * SEQ, 3 * DIM, DIM, 1.0f, 0, 0, 0);
    // expS = exp(QK^T/32 * gmask); row sums -> rsum               (512 blocks)
    mfma_gemm<EPI_EXP><<<dim3(SEQ / 256, SEQ / 128, 4), blk, 0, stream>>>(
        Qh, Qh + MD, nullptr, nullptr, expS, rsum, SEQ, SEQ, DIM, 0.03125f, SD, SD, SS);
    // O1 = (expS @ V) / rsum                                      (256 blocks)
    mfma_gemm<EPI_PV><<<dim3(DIM / 256, SEQ / 128, 4), blk, 0, stream>>>(
        expS, VT, nullptr, nullptr, O1, rsum, SEQ, DIM, SEQ, 1.0f, SS, (long)DIM * SEQ, SD);
    // out = O1 @ Wo^T + bo (fp32)                                 (256 blocks)
    mfma_gemm<EPI_OUT><<<dim3(DIM / 256, (4 * SEQ) / 128, 1), blk, 0, stream>>>(
        O1, Woh, bo, out, nullptr, nullptr, 4 * SEQ, DIM, DIM, 1.0f, 0, 0, 0);
}

// Round 3
// 282.697 us; speedup vs baseline: 1.0423x; 1.0423x over previous
//
#include <hip/hip_runtime.h>
#include <math.h>

#define SEQ 2048
#define DIM 1024

typedef __attribute__((ext_vector_type(8))) _Float16 half8;
typedef __attribute__((ext_vector_type(4))) float f32x4;

__device__ __forceinline__ unsigned short f2h(float f) {
    union { _Float16 h; unsigned short u; } c; c.h = (_Float16)f;
    return c.u;
}
__device__ __forceinline__ float h2f(unsigned short u) {
    union { unsigned short u2; _Float16 h; } c; c.u2 = u;
    return (float)c.h;
}
__device__ __forceinline__ float gmask(int k) {
    float t = ((float)k - 1024.0f) * (1.0f / 512.0f);
    return expf(-0.5f * t * t);
}
__device__ __forceinline__ void glds16(const unsigned short* gp, unsigned short* lp) {
    __builtin_amdgcn_global_load_lds((const __attribute__((address_space(1))) void*)gp,
                                     (__attribute__((address_space(3))) void*)lp, 16, 0, 0);
}

// Stage a 128x64 fp16 tile (16 KB) from global (row stride ldK) into lds.
// Row r = 64 elems (8 slots of 16B); LDS slot g^(r&7) holds global seg g.
// With the 16x16 fragment read pattern below this measured 0 bank conflicts;
// the 32x32 pattern conflicted -- do not switch back. (R0-proven; unchanged.)
__device__ __forceinline__ void stage64(const unsigned short* __restrict__ g, int ldK,
                                        unsigned short* lds, int wave, int lane) {
    int row = wave * 32 + (lane >> 3);
    int seg = (lane & 7) ^ (lane >> 3);
    const unsigned short* gp = g + (long)row * ldK + seg * 8;
    unsigned short* lp = lds + wave * 2048;
    glds16(gp, lp);
    glds16(gp + 8 * (long)ldK, lp + 512);
    glds16(gp + 16 * (long)ldK, lp + 1024);
    glds16(gp + 24 * (long)ldK, lp + 1536);
}

enum { EPI_QKV = 0, EPI_EXP = 1, EPI_PV = 2, EPI_OUT = 3 };

// C = A @ B^T with 16x16x32 fp16 MFMA. A:[M,K], B:[N,K] fp16 row-major.
// R0 structure (256 thr, 128x128 tile, single 32KB buffer, ~5 blocks/CU --
// the implicit inter-block overlap is the performance mechanism; R1/R2
// proved the 1-block/CU deep-pipeline variants lose at this geometry).
// Round-3 delta vs R0 (the only verified improvement from R1/R2):
//   - PV in-loop row-sum REMOVED; EXP epilogue accumulates rowsums of the
//     fp16-rounded exp into rsum[] via shfl-reduce + atomicAdd (pre-zeroed
//     in prep); PV epilogue multiplies by 1/rsum. Removes ~20% VALU/LDS
//     contention from PV's MFMA loop + one syncthreads.
// EPI_QKV: N=3072 packed; writes Q, K, V^T [b][d][s] (+bias).
// EPI_EXP: writes fp16 exp(acc*scale*gmask(n)); rowsums -> rsum.
// EPI_PV : writes fp16 acc * (1/rsum[row]).
// EPI_OUT: writes fp32 acc + bias(n).
template <int EPI>
__device__ __forceinline__ void gemm_body(
    const unsigned short* __restrict__ A, const unsigned short* __restrict__ Bm,
    const float* __restrict__ bias,
    float* __restrict__ Cf, unsigned short* __restrict__ Ch,
    float* __restrict__ rsum,
    int M, int N, int K, float scale, long sA, long sB, long sC)
{
    __shared__ unsigned short As[128 * 64];
    __shared__ unsigned short Bs[128 * 64];

    const int bz = blockIdx.z;
    const int tid = threadIdx.x;
    const int wave = tid >> 6;
    const int lane = tid & 63;
    const int wm = (wave & 1) * 64;
    const int wn = (wave >> 1) * 64;
    const long m0 = (long)blockIdx.y * 128;
    const long n0 = (long)blockIdx.x * 128;
    const int lm = lane & 15;
    const int lk = lane >> 4;

    const unsigned short* pA = A + bz * sA + m0 * K;
    const unsigned short* pB = Bm + bz * sB + n0 * K;

    f32x4 acc[4][4];
#pragma unroll
    for (int i = 0; i < 4; ++i)
#pragma unroll
        for (int j = 0; j < 4; ++j) {
            acc[i][j].x = 0.f; acc[i][j].y = 0.f; acc[i][j].z = 0.f; acc[i][j].w = 0.f;
        }

    // fragment LDS offsets (elems), swizzle applied: frag i, k-step t
    int aoff[4][2], boff[4][2];
#pragma unroll
    for (int i = 0; i < 4; ++i)
#pragma unroll
        for (int t = 0; t < 2; ++t) {
            int ar = wm + i * 16 + lm;
            aoff[i][t] = ar * 64 + (((4 * t + lk) ^ (ar & 7)) << 3);
            int br = wn + i * 16 + lm;
            boff[i][t] = br * 64 + (((4 * t + lk) ^ (br & 7)) << 3);
        }

    for (int k0 = 0; k0 < K; k0 += 64) {
        stage64(pA + k0, K, As, wave, lane);
        stage64(pB + k0, K, Bs, wave, lane);
        __syncthreads();

#pragma unroll
        for (int t = 0; t < 2; ++t) {
            half8 a[4], b[4];
#pragma unroll
            for (int i = 0; i < 4; ++i) a[i] = *(const half8*)(As + aoff[i][t]);
#pragma unroll
            for (int j = 0; j < 4; ++j) b[j] = *(const half8*)(Bs + boff[j][t]);
#pragma unroll
            for (int i = 0; i < 4; ++i)
#pragma unroll
                for (int j = 0; j < 4; ++j)
                    acc[i][j] = __builtin_amdgcn_mfma_f32_16x16x32_f16(a[i], b[j], acc[i][j], 0, 0, 0);
        }
        __syncthreads();
    }

    // ---- epilogue. C/D layout: col = lane&15, row = (lane>>4)*4 + r  [m89/m91]
    const long MD = 8388608;  // 4*SEQ*DIM
    float* cF = (EPI == EPI_OUT) ? Cf + bz * sC : (float*)nullptr;
    unsigned short* cH = (EPI != EPI_OUT) ? Ch + bz * sC : (unsigned short*)nullptr;

#pragma unroll
    for (int i = 0; i < 4; ++i) {
        long mrow = m0 + wm + i * 16 + lk * 4;   // rows mrow..mrow+3
        float inv4[4];
        if (EPI == EPI_PV) {
#pragma unroll
            for (int r = 0; r < 4; ++r)
                inv4[r] = 1.0f / rsum[(long)bz * SEQ + mrow + r];
        }
        float rsv[4] = {0.f, 0.f, 0.f, 0.f};
#pragma unroll
        for (int j = 0; j < 4; ++j) {
            int n = (int)n0 + wn + j * 16 + lm;
            if (EPI == EPI_QKV) {
                int sel = n >> 10;   // block-uniform (n0 multiple of 128)
                int n1 = n & 1023;
                float bs = bias[n];
                if (sel < 2) {
                    unsigned short* dst = cH + (long)sel * MD;
#pragma unroll
                    for (int r = 0; r < 4; ++r)
                        dst[(mrow + r) * (long)DIM + n1] = f2h(acc[i][j][r] + bs);
                } else {
                    long b = mrow >> 11, s = mrow & 2047;
                    long idx = 2 * MD + b * (long)DIM * SEQ + (long)n1 * SEQ + s;
                    unsigned long long pk =
                        (unsigned long long)f2h(acc[i][j].x + bs) |
                        ((unsigned long long)f2h(acc[i][j].y + bs) << 16) |
                        ((unsigned long long)f2h(acc[i][j].z + bs) << 32) |
                        ((unsigned long long)f2h(acc[i][j].w + bs) << 48);
                    *(unsigned long long*)(cH + idx) = pk;
                }
            } else if (EPI == EPI_EXP) {
                float mult = scale * gmask(n);
#pragma unroll
                for (int r = 0; r < 4; ++r) {
                    float e = expf(acc[i][j][r] * mult);
                    unsigned short h = f2h(e);
                    cH[(mrow + r) * (long)N + n] = h;
                    rsv[r] += h2f(h);   // sum the fp16-rounded value (matches PV read)
                }
            } else if (EPI == EPI_PV) {
#pragma unroll
                for (int r = 0; r < 4; ++r)
                    cH[(mrow + r) * (long)N + n] = f2h(acc[i][j][r] * inv4[r]);
            } else {  // EPI_OUT
                float bs = bias[n];
#pragma unroll
                for (int r = 0; r < 4; ++r)
                    cF[(mrow + r) * (long)N + n] = acc[i][j][r] + bs;
            }
        }
        if (EPI == EPI_EXP) {
            // reduce the per-thread partials over the 16 lm-lanes (lk fixed)
#pragma unroll
            for (int r = 0; r < 4; ++r) {
#pragma unroll
                for (int msk = 1; msk < 16; msk <<= 1)
                    rsv[r] += __shfl_xor(rsv[r], msk, 64);
            }
            if (lm == 0) {
#pragma unroll
                for (int r = 0; r < 4; ++r)
                    atomicAdd(rsum + (long)bz * SEQ + mrow + r, rsv[r]);
            }
        }
    }
}

// Distinct names for per-stage rocprof attribution (bodies identical).
__global__ __launch_bounds__(256, 4) void gemm_qkv(
    const unsigned short* __restrict__ A, const unsigned short* __restrict__ Bm,
    const float* __restrict__ bias, float* __restrict__ Cf, unsigned short* __restrict__ Ch,
    float* __restrict__ rsum, int M, int N, int K, float scale, long sA, long sB, long sC)
{ gemm_body<EPI_QKV>(A, Bm, bias, Cf, Ch, rsum, M, N, K, scale, sA, sB, sC); }

__global__ __launch_bounds__(256, 4) void gemm_exp(
    const unsigned short* __restrict__ A, const unsigned short* __restrict__ Bm,
    const float* __restrict__ bias, float* __restrict__ Cf, unsigned short* __restrict__ Ch,
    float* __restrict__ rsum, int M, int N, int K, float scale, long sA, long sB, long sC)
{ gemm_body<EPI_EXP>(A, Bm, bias, Cf, Ch, rsum, M, N, K, scale, sA, sB, sC); }

__global__ __launch_bounds__(256, 4) void gemm_pv(
    const unsigned short* __restrict__ A, const unsigned short* __restrict__ Bm,
    const float* __restrict__ bias, float* __restrict__ Cf, unsigned short* __restrict__ Ch,
    float* __restrict__ rsum, int M, int N, int K, float scale, long sA, long sB, long sC)
{ gemm_body<EPI_PV>(A, Bm, bias, Cf, Ch, rsum, M, N, K, scale, sA, sB, sC); }

__global__ __launch_bounds__(256, 4) void gemm_out(
    const unsigned short* __restrict__ A, const unsigned short* __restrict__ Bm,
    const float* __restrict__ bias, float* __restrict__ Cf, unsigned short* __restrict__ Ch,
    float* __restrict__ rsum, int M, int N, int K, float scale, long sA, long sB, long sC)
{ gemm_body<EPI_OUT>(A, Bm, bias, Cf, Ch, rsum, M, N, K, scale, sA, sB, sC); }

// One-shot prep: x -> fp16, pack Wq|Wk|Wv|Wo -> fp16, pack bq|bk|bv -> fp32,
// zero rsum[4*SEQ] (EXP atomically accumulates into it each launch).
__global__ __launch_bounds__(256) void prep(
    const float* __restrict__ x,
    const float* __restrict__ Wq, const float* __restrict__ Wk,
    const float* __restrict__ Wv, const float* __restrict__ Wo,
    const float* __restrict__ b0, const float* __restrict__ b1, const float* __restrict__ b2,
    unsigned short* __restrict__ xh, unsigned short* __restrict__ Wp,
    float* __restrict__ bqkv, float* __restrict__ rsum)
{
    long gid = (long)blockIdx.x * 256 + threadIdx.x;
    if (gid < 3072) {
        int sel = (int)(gid >> 10);
        const float* s = sel == 0 ? b0 : sel == 1 ? b1 : b2;
        bqkv[gid] = s[gid & 1023];
    }
    if (gid < 4 * SEQ) rsum[gid] = 0.f;
    const long NX = 8388608 / 4;   // x float4 count
    const long NW = 1048576 / 4;   // per-weight float4 count (2^18)
    const long total = NX + 4 * NW;
    for (long i = gid; i < total; i += (long)gridDim.x * 256) {
        const float* src; unsigned short* dst; long off;
        if (i < NX) { src = x; dst = xh; off = i; }
        else {
            long wi = i - NX;
            int sel = (int)(wi >> 18);
            src = sel == 0 ? Wq : sel == 1 ? Wk : sel == 2 ? Wv : Wo;
            dst = Wp + ((long)sel << 20);
            off = wi & (NW - 1);
        }
        float4 v = ((const float4*)src)[off];
        unsigned long long p = (unsigned long long)f2h(v.x) | ((unsigned long long)f2h(v.y) << 16) |
                               ((unsigned long long)f2h(v.z) << 32) | ((unsigned long long)f2h(v.w) << 48);
        ((unsigned long long*)dst)[off] = p;
    }
}

extern "C" void kernel_launch(void* const* d_in, const int* in_sizes, int n_in,
                              void* d_out, int out_size, void* d_ws, size_t ws_size,
                              hipStream_t stream)
{
    const float* x  = (const float*)d_in[0];
    const float* Wq = (const float*)d_in[1];
    const float* bq = (const float*)d_in[2];
    const float* Wk = (const float*)d_in[3];
    const float* bk = (const float*)d_in[4];
    const float* Wv = (const float*)d_in[5];
    const float* bv = (const float*)d_in[6];
    const float* Wo = (const float*)d_in[7];
    const float* bo = (const float*)d_in[8];
    float* out = (float*)d_out;

    const long MD = 4L * SEQ * DIM;    // 8M
    const long WW = (long)DIM * DIM;   // 1M
    const long SD = (long)SEQ * DIM, SS = (long)SEQ * SEQ;

    unsigned short* xh   = (unsigned short*)d_ws;           // 16 MB
    unsigned short* Wp   = xh + MD;                         // 8 MB (Wqkv|Wo fp16)
    unsigned short* Woh  = Wp + 3 * WW;
    float* bqkv          = (float*)(Wp + 4 * WW);           // 3072 (+pad)
    unsigned short* Qh   = (unsigned short*)(bqkv + 4096);  // Q|K|VT contiguous 48 MB
    unsigned short* VT   = Qh + 2 * MD;                     // [B][D][S]
    unsigned short* expS = Qh + 3 * MD;                     // 33.5 MB
    float* rsum          = (float*)(expS + 4 * SS);         // 4*SEQ fp32 (32 KB)
    unsigned short* O1   = xh;                              // alias: x dead after QKV

    dim3 blk(256);
    prep<<<4096, blk, 0, stream>>>(x, Wq, Wk, Wv, Wo, bq, bk, bv, xh, Wp, bqkv, rsum);

    // QKV fused: [8192,3072] = x @ Wqkv^T + bqkv -> Q, K, V^T   (1536 blocks)
    gemm_qkv<<<dim3(3 * DIM / 128, (4 * SEQ) / 128, 1), blk, 0, stream>>>(
        xh, Wp, bqkv, nullptr, Qh, nullptr, 4 * SEQ, 3 * DIM, DIM, 1.0f, 0, 0, 0);
    // expS = exp(QK^T/32 * gmask); rowsums -> rsum              (1024 blocks)
    gemm_exp<<<dim3(SEQ / 128, SEQ / 128, 4), blk, 0, stream>>>(
        Qh, Qh + MD, nullptr, nullptr, expS, rsum, SEQ, SEQ, DIM, 0.03125f, SD, SD, SS);
    // O1 = (expS @ V) / rsum                                     (512 blocks)
    gemm_pv<<<dim3(DIM / 128, SEQ / 128, 4), blk, 0, stream>>>(
        expS, VT, nullptr, nullptr, O1, rsum, SEQ, DIM, SEQ, 1.0f, SS, (long)DIM * SEQ, SD);
    // out = O1 @ Wo^T + bo (fp32)                                (512 blocks)
    gemm_out<<<dim3(DIM / 128, (4 * SEQ) / 128, 1), blk, 0, stream>>>(
        O1, Woh, bo, out, nullptr, nullptr, 4 * SEQ, DIM, DIM, 1.0f, 0, 0, 0);
}